// Round 4
// baseline (116.766 us; speedup 1.0000x reference)
//
#include <hip/hip_runtime.h>
#include <hip/hip_fp16.h>

#define BLOCK 256
#define MAIN_BLOCKS_NOF 4096     // fallback (no-filter) config
#define FBLOCK 1024              // filtered main: 1024 thr, 1 block/CU
#define FGRID 256                // exactly one block per CU
#define NWAVES (FBLOCK / 64)

// Fused prep: packed atom record (x,y,z,[sigma_f16|sqrt(eps)_f16]) + cell id.
// Cell grid 8x8x4 (3+3+2 bits = 1 byte). Cell sizes L/8, L/8, L/4.
// Also zeroes out[0] (harness poisons d_out before every launch).
__global__ void lj_prep_kernel(const float* __restrict__ coords,
                               const float* __restrict__ sigma,
                               const float* __restrict__ eps,
                               const float* __restrict__ box,
                               float4* __restrict__ table,
                               unsigned char* __restrict__ cellg,
                               float* __restrict__ out,
                               int n_atoms) {
    int i = blockIdx.x * blockDim.x + threadIdx.x;
    if (i == 0) out[0] = 0.0f;   // stream-ordered before main's atomicAdd
    if (i >= n_atoms) return;
    float x = coords[3 * i + 0];
    float y = coords[3 * i + 1];
    float z = coords[3 * i + 2];
    float s  = sigma[i];
    float se = sqrtf(eps[i]);
    unsigned pack = (unsigned)__half_as_ushort(__float2half(s)) |
                    ((unsigned)__half_as_ushort(__float2half(se)) << 16);
    table[i] = make_float4(x, y, z, __uint_as_float(pack));

    float L0 = box[0], L1 = box[4], L2 = box[8];
    int cx = min((int)(x * (8.0f / L0)), 7); cx = max(cx, 0);
    int cy = min((int)(y * (8.0f / L1)), 7); cy = max(cy, 0);
    int cz = min((int)(z * (4.0f / L2)), 3); cz = max(cz, 0);
    cellg[i] = (unsigned char)(cx | (cy << 3) | (cz << 6));
}

__device__ __forceinline__ float lj_energy(float4 pi, float4 pj,
                                           float L0, float L1, float L2,
                                           float b0, float b1, float b2,
                                           float c2) {
    float dx = pi.x - pj.x;
    float dy = pi.y - pj.y;
    float dz = pi.z - pj.z;
    float sx = dx * b0; sx -= floorf(sx + 0.5f); dx = sx * L0;
    float sy = dy * b1; sy -= floorf(sy + 0.5f); dy = sy * L1;
    float sz = dz * b2; sz -= floorf(sz + 0.5f); dz = sz * L2;
    float r2 = dx * dx + dy * dy + dz * dz;

    unsigned packi = __float_as_uint(pi.w);
    unsigned packj = __float_as_uint(pj.w);
    float si  = __half2float(__ushort_as_half((unsigned short)(packi & 0xffffu)));
    float sj  = __half2float(__ushort_as_half((unsigned short)(packj & 0xffffu)));
    float sei = __half2float(__ushort_as_half((unsigned short)(packi >> 16)));
    float sej = __half2float(__ushort_as_half((unsigned short)(packj >> 16)));

    float sij   = (si + sj) * 0.5f;
    float epsij = sei * sej;            // sqrt(eps_i)*sqrt(eps_j)
    float ratio = (sij * sij) / r2;     // (sigma_ij/dr)^2
    float t     = ratio * ratio * ratio;
    float e     = 4.0f * epsij * t * (t - 1.0f);
    return (r2 <= c2) ? e : 0.0f;
}

__device__ __forceinline__ bool cell_near(unsigned ci, unsigned cj) {
    unsigned dcx = (ci - cj) & 7u;
    unsigned dcy = ((ci >> 3) - (cj >> 3)) & 7u;
    unsigned dcz = ((ci >> 6) - (cj >> 6)) & 3u;
    return (dcx <= 1u || dcx == 7u) &&
           (dcy <= 1u || dcy == 7u) &&
           (dcz <= 1u || dcz == 3u);
}

// Filtered main v5: DIRECT MASKED EVALUATION — queue/ballot machinery deleted.
// Ablation rationale: 3 consecutive scheduling nulls (r1-r3) prove main's
// ~30us is invariant to load pipelining; the un-ablated component is the
// compaction web (ballot->mbcnt->scalar qcount->ds_write->drain ds_read +
// 6 branches/iter). Exec-masked gathers issue NO memory requests, so direct
// evaluation at ~10% lane density has IDENTICAL L1 traffic to the compacted
// drain, and the masked LJ VALU lands in a pipe that is ~87% idle.
//  - per-atom cell bytes staged in LDS (100 KB; global byte-gathers proved
//    L1-port-bound in r1: 64-line fan-out per wave-gather)
//  - contiguous per-wave pair slices (sequential loads), prefetch-1
__global__ __launch_bounds__(FBLOCK) void lj_main_direct(
        const int4* __restrict__ pairs4,
        const int2* __restrict__ pairs2,
        const float4* __restrict__ table,
        const unsigned char* __restrict__ cellg,
        const float* __restrict__ box,
        const int* __restrict__ cutoff,
        float* __restrict__ out,
        int n_atoms, int n4, int n_pairs) {
    extern __shared__ unsigned char lds[];
    unsigned char* cellLds = lds;
    int lane = threadIdx.x & 63;
    int wid  = threadIdx.x >> 6;

    // cooperative LDS fill of cell bytes, 16B per thread per iter
    int n16 = n_atoms >> 4;
    const uint4* src = (const uint4*)cellg;
    uint4* dst = (uint4*)cellLds;
    for (int k = threadIdx.x; k < n16; k += blockDim.x) dst[k] = src[k];
    for (int k = (n16 << 4) + threadIdx.x; k < n_atoms; k += blockDim.x)
        cellLds[k] = cellg[k];
    __syncthreads();

    const float L0 = box[0], L1 = box[4], L2 = box[8];
    const float b0 = 1.0f / L0, b1 = 1.0f / L1, b2 = 1.0f / L2;
    const float c  = (float)cutoff[0];
    const float c2 = c * c;
    // filter validity: cell sizes must be >= cutoff on every axis
    const bool use_filter = (c <= L0 * 0.125f) && (c <= L1 * 0.125f) &&
                            (c <= L2 * 0.25f);

    float acc = 0.0f;

    // contiguous slice of int4 units for this wave
    int nW = FGRID * NWAVES;
    int per_wave = (n4 + nW - 1) / nW;
    int gwid  = blockIdx.x * NWAVES + wid;
    int p     = gwid * per_wave;
    int pend  = min(p + per_wave, n4);

    bool v = (p + lane) < pend;
    int4 pp = v ? pairs4[p + lane] : make_int4(0, 0, 0, 0);

    while (p < pend) {
        int np = p + 64;
        bool vn = (np + lane) < pend;
        int4 ppn = vn ? pairs4[np + lane] : make_int4(0, 0, 0, 0);

        unsigned ca = cellLds[pp.x];
        unsigned cb = cellLds[pp.y];
        unsigned cc = cellLds[pp.z];
        unsigned cd = cellLds[pp.w];

        if (v && (!use_filter || cell_near(ca, cb))) {
            float4 pi = table[pp.x];
            float4 pj = table[pp.y];
            acc += lj_energy(pi, pj, L0, L1, L2, b0, b1, b2, c2);
        }
        if (v && (!use_filter || cell_near(cc, cd))) {
            float4 pi = table[pp.z];
            float4 pj = table[pp.w];
            acc += lj_energy(pi, pj, L0, L1, L2, b0, b1, b2, c2);
        }

        p = np; pp = ppn; v = vn;
    }
    // odd tail pair (not covered by int4 view)
    if (blockIdx.x == 0 && threadIdx.x == 0 && (n_pairs & 1)) {
        int2 e = pairs2[n_pairs - 1];
        acc += lj_energy(table[e.x], table[e.y], L0, L1, L2, b0, b1, b2, c2);
    }

    // wave (64-lane) reduction
    for (int off = 32; off > 0; off >>= 1)
        acc += __shfl_down(acc, off, 64);

    __shared__ float wsum[NWAVES];
    if (lane == 0) wsum[wid] = acc;
    __syncthreads();
    if (threadIdx.x == 0) {
        float s = 0.0f;
        for (int w = 0; w < NWAVES; w++) s += wsum[w];
        atomicAdd(out, s);
    }
}

// Fallback main (R1 structure) if workspace/LDS can't hold the tables.
__global__ __launch_bounds__(BLOCK) void lj_main_kernel(
        const int2* __restrict__ pairs,
        const float4* __restrict__ table,
        const float* __restrict__ box,
        const int* __restrict__ cutoff,
        float* __restrict__ out,
        int n_pairs) {
    const float L0 = box[0], L1 = box[4], L2 = box[8];
    const float b0 = 1.0f / L0, b1 = 1.0f / L1, b2 = 1.0f / L2;
    const float c  = (float)cutoff[0];
    const float c2 = c * c;

    float acc = 0.0f;
    int tid = blockIdx.x * blockDim.x + threadIdx.x;
    int stride = gridDim.x * blockDim.x;
    for (int p = tid; p < n_pairs; p += stride) {
        int2 ij = pairs[p];
        float4 pi = table[ij.x];
        float4 pj = table[ij.y];
        acc += lj_energy(pi, pj, L0, L1, L2, b0, b1, b2, c2);
    }
    for (int off = 32; off > 0; off >>= 1)
        acc += __shfl_down(acc, off, 64);
    __shared__ float wsum[BLOCK / 64];
    int lane = threadIdx.x & 63;
    int wid  = threadIdx.x >> 6;
    if (lane == 0) wsum[wid] = acc;
    __syncthreads();
    if (threadIdx.x == 0) {
        float s = 0.0f;
        for (int w = 0; w < BLOCK / 64; w++) s += wsum[w];
        atomicAdd(out, s);
    }
}

extern "C" void kernel_launch(void* const* d_in, const int* in_sizes, int n_in,
                              void* d_out, int out_size, void* d_ws, size_t ws_size,
                              hipStream_t stream) {
    const float* coords = (const float*)d_in[0];
    const int*   pairsi = (const int*)d_in[1];
    const float* box    = (const float*)d_in[2];
    const float* sigma  = (const float*)d_in[3];
    const float* eps    = (const float*)d_in[4];
    const int*   cutoff = (const int*)d_in[5];
    int n_atoms = in_sizes[0] / 3;
    int n_pairs = in_sizes[1] / 2;
    float* out = (float*)d_out;

    size_t table_bytes = ((size_t)n_atoms * sizeof(float4) + 255) & ~(size_t)255;
    size_t cell_bytes  = (size_t)n_atoms;
    float4* table = (float4*)d_ws;
    unsigned char* cellg = (unsigned char*)d_ws + table_bytes;

    int shmem = (n_atoms + 15) & ~15;   // cell bytes only (queue deleted)

    lj_prep_kernel<<<(n_atoms + 255) / 256, 256, 0, stream>>>(
        coords, sigma, eps, box, table, cellg, out, n_atoms);

    bool can_filter = (ws_size >= table_bytes + cell_bytes) &&
                      (shmem <= 160 * 1024 - 1024);

    if (can_filter) {
        static bool attr_set = false;  // host-side, idempotent, same every call
        if (!attr_set) {
            hipFuncSetAttribute((const void*)lj_main_direct,
                                hipFuncAttributeMaxDynamicSharedMemorySize,
                                shmem);
            attr_set = true;
        }
        lj_main_direct<<<FGRID, FBLOCK, shmem, stream>>>(
            (const int4*)pairsi, (const int2*)pairsi, table, cellg, box,
            cutoff, out, n_atoms, n_pairs / 2, n_pairs);
    } else {
        lj_main_kernel<<<MAIN_BLOCKS_NOF, BLOCK, 0, stream>>>(
            (const int2*)pairsi, table, box, cutoff, out, n_pairs);
    }
}

// Round 6
// 105.137 us; speedup vs baseline: 1.1106x; 1.1106x over previous
//
#include <hip/hip_runtime.h>
#include <hip/hip_fp16.h>

#define BLOCK 256
#define MAIN_BLOCKS_NOF 4096     // fallback (no-filter) config
#define FBLOCK 1024              // filtered main: 1024 thr, 1 block/CU
#define FGRID 256                // exactly one block per CU
#define NWAVES (FBLOCK / 64)
#define QCAP 256                 // per-wave ring queue (int2); count stays <= 255

// Fused prep: packed atom record (x,y,z,[sigma_f16|sqrt(eps)_f16]) + cell id.
// Cell grid 8x8x4 (3+3+2 bits = 1 byte). Cell sizes L/8, L/8, L/4.
// Also zeroes out[0] (harness poisons d_out before every launch).
__global__ void lj_prep_kernel(const float* __restrict__ coords,
                               const float* __restrict__ sigma,
                               const float* __restrict__ eps,
                               const float* __restrict__ box,
                               float4* __restrict__ table,
                               unsigned char* __restrict__ cellg,
                               float* __restrict__ out,
                               int n_atoms) {
    int i = blockIdx.x * blockDim.x + threadIdx.x;
    if (i == 0) out[0] = 0.0f;   // stream-ordered before main's atomicAdd
    if (i >= n_atoms) return;
    float x = coords[3 * i + 0];
    float y = coords[3 * i + 1];
    float z = coords[3 * i + 2];
    float s  = sigma[i];
    float se = sqrtf(eps[i]);
    unsigned pack = (unsigned)__half_as_ushort(__float2half(s)) |
                    ((unsigned)__half_as_ushort(__float2half(se)) << 16);
    table[i] = make_float4(x, y, z, __uint_as_float(pack));

    float L0 = box[0], L1 = box[4], L2 = box[8];
    int cx = min((int)(x * (8.0f / L0)), 7); cx = max(cx, 0);
    int cy = min((int)(y * (8.0f / L1)), 7); cy = max(cy, 0);
    int cz = min((int)(z * (4.0f / L2)), 3); cz = max(cz, 0);
    cellg[i] = (unsigned char)(cx | (cy << 3) | (cz << 6));
}

__device__ __forceinline__ float lj_energy(float4 pi, float4 pj,
                                           float L0, float L1, float L2,
                                           float b0, float b1, float b2,
                                           float c2) {
    float dx = pi.x - pj.x;
    float dy = pi.y - pj.y;
    float dz = pi.z - pj.z;
    float sx = dx * b0; sx -= floorf(sx + 0.5f); dx = sx * L0;
    float sy = dy * b1; sy -= floorf(sy + 0.5f); dy = sy * L1;
    float sz = dz * b2; sz -= floorf(sz + 0.5f); dz = sz * L2;
    float r2 = dx * dx + dy * dy + dz * dz;

    unsigned packi = __float_as_uint(pi.w);
    unsigned packj = __float_as_uint(pj.w);
    float si  = __half2float(__ushort_as_half((unsigned short)(packi & 0xffffu)));
    float sj  = __half2float(__ushort_as_half((unsigned short)(packj & 0xffffu)));
    float sei = __half2float(__ushort_as_half((unsigned short)(packi >> 16)));
    float sej = __half2float(__ushort_as_half((unsigned short)(packj >> 16)));

    float sij   = (si + sj) * 0.5f;
    float epsij = sei * sej;            // sqrt(eps_i)*sqrt(eps_j)
    float ratio = (sij * sij) / r2;     // (sigma_ij/dr)^2
    float t     = ratio * ratio * ratio;
    float e     = 4.0f * epsij * t * (t - 1.0f);
    return (r2 <= c2) ? e : 0.0f;
}

__device__ __forceinline__ bool cell_near(unsigned ci, unsigned cj) {
    unsigned dcx = (ci - cj) & 7u;
    unsigned dcy = ((ci >> 3) - (cj >> 3)) & 7u;
    unsigned dcz = ((ci >> 6) - (cj >> 6)) & 3u;
    return (dcx <= 1u || dcx == 7u) &&
           (dcy <= 1u || dcy == 7u) &&
           (dcz <= 1u || dcz == 3u);
}

// 64-lane prefix population count of a ballot mask (2 VALU ops).
__device__ __forceinline__ int prefix_cnt(unsigned long long bal) {
    return (int)__builtin_amdgcn_mbcnt_hi(
        (unsigned)(bal >> 32),
        __builtin_amdgcn_mbcnt_lo((unsigned)bal, 0u));
}

// Filtered + compacted main v6: shorten the per-wave serial critical path.
// Model fitting r0-r4: main ~= serial chain x ~2.7 overlap-inefficiency
// (4 waves/SIMD in lockstep phases can't hide each other's stalls).
// Changes vs r0 (the best-measured structure, ~30us):
//  (1) LDS fill batched: 7 INDEPENDENT guarded uint4 loads (static indices,
//      no runtime-indexed array -> no scratch), ONE wait, 7 ds_writes.
//      r0's copy loop serialized ~7 global latencies behind the barrier.
//  (2) 256 pairs/wave/iter (two int4 chunks): 6 iterations instead of 12,
//      8 cell gathers in flight per step, half the ballot/branch web count.
//      Ring invariant: drain after each 128-pair section -> qcount <= 191.
//  (3) queue + drain KEPT (r4 proved compaction is worth ~12us vs masked).
__global__ __launch_bounds__(FBLOCK) void lj_main_filtered(
        const int4* __restrict__ pairs4,
        const int2* __restrict__ pairs2,
        const float4* __restrict__ table,
        const unsigned char* __restrict__ cellg,
        const float* __restrict__ box,
        const int* __restrict__ cutoff,
        float* __restrict__ out,
        int n_atoms, int n4, int n_pairs, int qoff) {
    extern __shared__ unsigned char lds[];
    unsigned char* cellLds = lds;
    int lane = threadIdx.x & 63;
    int wid  = threadIdx.x >> 6;
    int2* queue = (int2*)(lds + qoff) + wid * QCAP;

    // ---- batched cell-table fill: one latency exposure ----
    {
        int n16 = n_atoms >> 4;
        const uint4* src = (const uint4*)cellg;
        uint4* dst = (uint4*)cellLds;
        int k0 = threadIdx.x;
        int k1 = k0 + FBLOCK, k2 = k1 + FBLOCK, k3 = k2 + FBLOCK;
        int k4 = k3 + FBLOCK, k5 = k4 + FBLOCK, k6 = k5 + FBLOCK;
        uint4 r0, r1, r2, r3, r4, r5, r6;
        if (k0 < n16) r0 = src[k0];
        if (k1 < n16) r1 = src[k1];
        if (k2 < n16) r2 = src[k2];
        if (k3 < n16) r3 = src[k3];
        if (k4 < n16) r4 = src[k4];
        if (k5 < n16) r5 = src[k5];
        if (k6 < n16) r6 = src[k6];
        if (k0 < n16) dst[k0] = r0;
        if (k1 < n16) dst[k1] = r1;
        if (k2 < n16) dst[k2] = r2;
        if (k3 < n16) dst[k3] = r3;
        if (k4 < n16) dst[k4] = r4;
        if (k5 < n16) dst[k5] = r5;
        if (k6 < n16) dst[k6] = r6;
        for (int k = k6 + FBLOCK; k < n16; k += FBLOCK) dst[k] = src[k];
        for (int k = (n16 << 4) + threadIdx.x; k < n_atoms; k += FBLOCK)
            cellLds[k] = cellg[k];
    }
    __syncthreads();

    const float L0 = box[0], L1 = box[4], L2 = box[8];
    const float b0 = 1.0f / L0, b1 = 1.0f / L1, b2 = 1.0f / L2;
    const float c  = (float)cutoff[0];
    const float c2 = c * c;
    // filter validity: cell sizes must be >= cutoff on every axis
    const bool use_filter = (c <= L0 * 0.125f) && (c <= L1 * 0.125f) &&
                            (c <= L2 * 0.25f);

    float acc = 0.0f;
    int qcount = 0, head = 0;

    int base = (blockIdx.x * NWAVES + wid) * 128;   // int4 units, 2 chunks/iter
    int step = FGRID * NWAVES * 128;

    bool vA = (base + lane) < n4;
    bool vB = (base + 64 + lane) < n4;
    int4 ppA = vA ? pairs4[base + lane]      : make_int4(0, 0, 0, 0);
    int4 ppB = vB ? pairs4[base + 64 + lane] : make_int4(0, 0, 0, 0);

    while (base < n4) {
        // prefetch next iteration's two chunks
        int nbase = base + step;
        bool vnA = (nbase + lane) < n4;
        bool vnB = (nbase + 64 + lane) < n4;
        int4 pnA = vnA ? pairs4[nbase + lane]      : make_int4(0, 0, 0, 0);
        int4 pnB = vnB ? pairs4[nbase + 64 + lane] : make_int4(0, 0, 0, 0);

        // 8 independent cell gathers in flight
        unsigned ca0 = cellLds[ppA.x], ca1 = cellLds[ppA.y];
        unsigned ca2 = cellLds[ppA.z], ca3 = cellLds[ppA.w];
        unsigned cb0 = cellLds[ppB.x], cb1 = cellLds[ppB.y];
        unsigned cb2 = cellLds[ppB.z], cb3 = cellLds[ppB.w];

        // ---- section A (128 pairs) ----
        {
            bool near0 = vA && (!use_filter || cell_near(ca0, ca1));
            unsigned long long bal0 = __ballot(near0);
            int pos0 = prefix_cnt(bal0);
            if (near0) queue[(head + qcount + pos0) & (QCAP - 1)] = make_int2(ppA.x, ppA.y);
            qcount += (int)__popcll(bal0);

            bool near1 = vA && (!use_filter || cell_near(ca2, ca3));
            unsigned long long bal1 = __ballot(near1);
            int pos1 = prefix_cnt(bal1);
            if (near1) queue[(head + qcount + pos1) & (QCAP - 1)] = make_int2(ppA.z, ppA.w);
            qcount += (int)__popcll(bal1);

            while (qcount >= 64) {   // wave-uniform
                int2 e = queue[(head + lane) & (QCAP - 1)];
                float4 pi = table[e.x];
                float4 pj = table[e.y];
                acc += lj_energy(pi, pj, L0, L1, L2, b0, b1, b2, c2);
                head = (head + 64) & (QCAP - 1);
                qcount -= 64;
            }
        }
        // ---- section B (128 pairs) ----
        {
            bool near0 = vB && (!use_filter || cell_near(cb0, cb1));
            unsigned long long bal0 = __ballot(near0);
            int pos0 = prefix_cnt(bal0);
            if (near0) queue[(head + qcount + pos0) & (QCAP - 1)] = make_int2(ppB.x, ppB.y);
            qcount += (int)__popcll(bal0);

            bool near1 = vB && (!use_filter || cell_near(cb2, cb3));
            unsigned long long bal1 = __ballot(near1);
            int pos1 = prefix_cnt(bal1);
            if (near1) queue[(head + qcount + pos1) & (QCAP - 1)] = make_int2(ppB.z, ppB.w);
            qcount += (int)__popcll(bal1);

            while (qcount >= 64) {
                int2 e = queue[(head + lane) & (QCAP - 1)];
                float4 pi = table[e.x];
                float4 pj = table[e.y];
                acc += lj_energy(pi, pj, L0, L1, L2, b0, b1, b2, c2);
                head = (head + 64) & (QCAP - 1);
                qcount -= 64;
            }
        }

        base = nbase;
        ppA = pnA; ppB = pnB; vA = vnA; vB = vnB;
    }
    // drain remaining full groups + partial tail
    while (qcount >= 64) {
        int2 e = queue[(head + lane) & (QCAP - 1)];
        acc += lj_energy(table[e.x], table[e.y], L0, L1, L2, b0, b1, b2, c2);
        head = (head + 64) & (QCAP - 1);
        qcount -= 64;
    }
    if (lane < qcount) {
        int2 e = queue[(head + lane) & (QCAP - 1)];
        acc += lj_energy(table[e.x], table[e.y], L0, L1, L2, b0, b1, b2, c2);
    }
    // odd tail pair (not covered by int4 view)
    if (blockIdx.x == 0 && threadIdx.x == 0 && (n_pairs & 1)) {
        int2 e = pairs2[n_pairs - 1];
        acc += lj_energy(table[e.x], table[e.y], L0, L1, L2, b0, b1, b2, c2);
    }

    // wave (64-lane) reduction
    for (int off = 32; off > 0; off >>= 1)
        acc += __shfl_down(acc, off, 64);

    __shared__ float wsum[NWAVES];
    if (lane == 0) wsum[wid] = acc;
    __syncthreads();
    if (threadIdx.x == 0) {
        float s = 0.0f;
        for (int w = 0; w < NWAVES; w++) s += wsum[w];
        atomicAdd(out, s);
    }
}

// Fallback main (R1 structure) if workspace/LDS can't hold the tables.
__global__ __launch_bounds__(BLOCK) void lj_main_kernel(
        const int2* __restrict__ pairs,
        const float4* __restrict__ table,
        const float* __restrict__ box,
        const int* __restrict__ cutoff,
        float* __restrict__ out,
        int n_pairs) {
    const float L0 = box[0], L1 = box[4], L2 = box[8];
    const float b0 = 1.0f / L0, b1 = 1.0f / L1, b2 = 1.0f / L2;
    const float c  = (float)cutoff[0];
    const float c2 = c * c;

    float acc = 0.0f;
    int tid = blockIdx.x * blockDim.x + threadIdx.x;
    int stride = gridDim.x * blockDim.x;
    for (int p = tid; p < n_pairs; p += stride) {
        int2 ij = pairs[p];
        float4 pi = table[ij.x];
        float4 pj = table[ij.y];
        acc += lj_energy(pi, pj, L0, L1, L2, b0, b1, b2, c2);
    }
    for (int off = 32; off > 0; off >>= 1)
        acc += __shfl_down(acc, off, 64);
    __shared__ float wsum[BLOCK / 64];
    int lane = threadIdx.x & 63;
    int wid  = threadIdx.x >> 6;
    if (lane == 0) wsum[wid] = acc;
    __syncthreads();
    if (threadIdx.x == 0) {
        float s = 0.0f;
        for (int w = 0; w < BLOCK / 64; w++) s += wsum[w];
        atomicAdd(out, s);
    }
}

extern "C" void kernel_launch(void* const* d_in, const int* in_sizes, int n_in,
                              void* d_out, int out_size, void* d_ws, size_t ws_size,
                              hipStream_t stream) {
    const float* coords = (const float*)d_in[0];
    const int*   pairsi = (const int*)d_in[1];
    const float* box    = (const float*)d_in[2];
    const float* sigma  = (const float*)d_in[3];
    const float* eps    = (const float*)d_in[4];
    const int*   cutoff = (const int*)d_in[5];
    int n_atoms = in_sizes[0] / 3;
    int n_pairs = in_sizes[1] / 2;
    float* out = (float*)d_out;

    size_t table_bytes = ((size_t)n_atoms * sizeof(float4) + 255) & ~(size_t)255;
    size_t cell_bytes  = (size_t)n_atoms;
    float4* table = (float4*)d_ws;
    unsigned char* cellg = (unsigned char*)d_ws + table_bytes;

    int qoff = (n_atoms + 15) & ~15;
    int shmem = qoff + NWAVES * QCAP * (int)sizeof(int2);

    lj_prep_kernel<<<(n_atoms + 255) / 256, 256, 0, stream>>>(
        coords, sigma, eps, box, table, cellg, out, n_atoms);

    bool can_filter = (ws_size >= table_bytes + cell_bytes) &&
                      (shmem <= 160 * 1024 - 1024);

    if (can_filter) {
        static bool attr_set = false;  // host-side, idempotent, same every call
        if (!attr_set) {
            hipFuncSetAttribute((const void*)lj_main_filtered,
                                hipFuncAttributeMaxDynamicSharedMemorySize,
                                shmem);
            attr_set = true;
        }
        lj_main_filtered<<<FGRID, FBLOCK, shmem, stream>>>(
            (const int4*)pairsi, (const int2*)pairsi, table, cellg, box,
            cutoff, out, n_atoms, n_pairs / 2, n_pairs, qoff);
    } else {
        lj_main_kernel<<<MAIN_BLOCKS_NOF, BLOCK, 0, stream>>>(
            (const int2*)pairsi, table, box, cutoff, out, n_pairs);
    }
}